// Round 4
// baseline (105.692 us; speedup 1.0000x reference)
//
#include <hip/hip_runtime.h>
#include <cstdint>

#define B_ 32
#define C_ 2048
#define Q_ 128
#define D_ 128
#define CT 64
#define NEG_INF_F (-1.0e9f)

typedef __attribute__((ext_vector_type(8))) short bf16x8;
typedef __attribute__((ext_vector_type(4))) float f32x4;

__device__ inline void split_f32(float v, short& h, short& l) {
    unsigned u  = __float_as_uint(v);
    unsigned hb = u & 0xffff0000u;          // truncated bf16 (hi)
    float lo = v - __uint_as_float(hb);     // exact residual
    h = (short)(hb >> 16);
    l = (short)(__float_as_uint(lo) >> 16);
}

// ---------- prep: qw2e (q.w2 + mask), bf16-split of (qry*w3) and qry^T ----------
__global__ __launch_bounds__(256)
void cqa_prep(const float* __restrict__ qry, const float* __restrict__ w,
              const int* __restrict__ qmask, float* __restrict__ qw2e_g,
              unsigned short* __restrict__ qw3Hi, unsigned short* __restrict__ qw3Lo,
              unsigned short* __restrict__ qTHi, unsigned short* __restrict__ qTLo)
{
    const int b = blockIdx.y, ch = blockIdx.x;   // ch: 16-row chunk of q
    const int t = threadIdx.x;
    const float* qb = qry + (size_t)b * Q_ * D_;

    if (t < 32) {
        int rl = t >> 1, part = t & 1;
        int q = ch * 16 + rl;
        const float* p  = qb + q * D_ + part * 64;
        const float* wp = w + D_ + part * 64;
        float s = 0.f;
        #pragma unroll
        for (int j = 0; j < 64; j += 4) {
            float4 a4 = *(const float4*)(p + j);
            float4 w4 = *(const float4*)(wp + j);
            s += a4.x*w4.x + a4.y*w4.y + a4.z*w4.z + a4.w*w4.w;
        }
        s += __shfl_xor(s, 1, 2);
        if (!part) {
            float madd = (1.0f - (float)qmask[b * Q_ + q]) * NEG_INF_F;
            qw2e_g[b * Q_ + q] = s + madd;
        }
    }
    #pragma unroll
    for (int i = 0; i < 8; ++i) {
        int idx = t + i * 256;            // 0..2047 over 16 rows x 128 d
        int ql = idx >> 7, d = idx & 127;
        int q = ch * 16 + ql;
        float v  = qb[q * D_ + d];
        float vw = v * w[2 * D_ + d];
        short h, l;
        split_f32(vw, h, l);
        qw3Hi[((size_t)b * Q_ + q) * D_ + d] = (unsigned short)h;
        qw3Lo[((size_t)b * Q_ + q) * D_ + d] = (unsigned short)l;
        split_f32(v, h, l);
        qTHi[((size_t)b * D_ + d) * Q_ + q] = (unsigned short)h;
        qTLo[((size_t)b * D_ + d) * Q_ + q] = (unsigned short)l;
    }
}

// ---------- main: MFMA S-GEMM + softmax + MFMA PV-GEMM + out[0:3D) ----------
__global__ __launch_bounds__(256, 2)
void cqa_main(const float* __restrict__ ctx, const float* __restrict__ w,
              const float* __restrict__ qw2e_g,
              const unsigned short* __restrict__ qw3Hi, const unsigned short* __restrict__ qw3Lo,
              const unsigned short* __restrict__ qTHi, const unsigned short* __restrict__ qTLo,
              float* __restrict__ out, float* __restrict__ m_out)
{
    __shared__ __align__(16) char smem[56320];
    short* CsHi = (short*)smem;                 // [64][40]  GEMM1
    short* CsLo = (short*)(smem + 5120);
    short* QbHi = (short*)(smem + 10240);       // [128][40] GEMM1
    short* QbLo = (short*)(smem + 20480);       // ..30720
    short* PHi  = (short*)smem;                 // [64][136] GEMM2 (overlays Cs/Qb)
    short* PLo  = (short*)(smem + 17408);       // ..34816
    short* QTh  = (short*)(smem + 34816);       // [128][40] GEMM2
    short* QTl  = (short*)(smem + 45056);       // ..55296
    float* Tr   = (float*)smem;                 // [64][132] epilogue (overlays P)
    float* cw1  = (float*)(smem + 55296);       // 64 f32
    float* qw2e = (float*)(smem + 55552);       // 128 f32

    const int b   = blockIdx.y;
    const int c0  = blockIdx.x * CT;
    const int tid = threadIdx.x;
    const int lane = tid & 63;
    const int wv   = tid >> 6;
    const int w16  = wv * 16;
    const int lm   = lane & 15;
    const int lg   = lane >> 4;    // 0..3
    const int lk   = lg * 8;       // k-slot start within 32-chunk

    const float* ctxb = ctx + ((size_t)b * C_ + c0) * D_;

    // cw1[c] = ctx_row . w1 (4 threads/row)
    {
        int row = tid >> 2, part = tid & 3;
        const float* p  = ctxb + row * D_ + part * 32;
        const float* wp = w + part * 32;
        float s = 0.f;
        #pragma unroll
        for (int j = 0; j < 32; j += 4) {
            float4 c4 = *(const float4*)(p + j);
            float4 w4 = *(const float4*)(wp + j);
            s += c4.x*w4.x + c4.y*w4.y + c4.z*w4.z + c4.w*w4.w;
        }
        s += __shfl_xor(s, 1, 4);
        s += __shfl_xor(s, 2, 4);
        if (!part) cw1[row] = s;
    }
    if (tid < Q_) qw2e[tid] = qw2e_g[b * Q_ + tid];
    __syncthreads();

    float qe[8];
    #pragma unroll
    for (int f = 0; f < 8; ++f) qe[f] = qw2e[f * 16 + lm];
    float cwr[4];
    #pragma unroll
    for (int r = 0; r < 4; ++r) cwr[r] = cw1[w16 + lg * 4 + r];

    const f32x4 vzero = {0.f, 0.f, 0.f, 0.f};
    f32x4 acc[8];
    #pragma unroll
    for (int f = 0; f < 8; ++f) acc[f] = vzero;

    const unsigned short* qw3Hb = qw3Hi + (size_t)b * Q_ * D_;
    const unsigned short* qw3Lb = qw3Lo + (size_t)b * Q_ * D_;

    // ---- GEMM1: S[c][q] (wave: 16 rows x 128 cols), K=d in 4 chunks of 32
    for (int k0 = 0; k0 < D_; k0 += 32) {
        __syncthreads();
        {   // stage ctx chunk 64x32 f32 -> bf16 hi/lo
            int row = tid >> 2, part = tid & 3;
            const float* p = ctxb + row * D_ + k0 + part * 8;
            float4 v0 = *(const float4*)p;
            float4 v1 = *(const float4*)(p + 4);
            float vv[8] = {v0.x,v0.y,v0.z,v0.w,v1.x,v1.y,v1.z,v1.w};
            bf16x8 h, l;
            #pragma unroll
            for (int i = 0; i < 8; ++i) { short hh, ll; split_f32(vv[i], hh, ll); h[i]=hh; l[i]=ll; }
            *(bf16x8*)(CsHi + row * 40 + part * 8) = h;
            *(bf16x8*)(CsLo + row * 40 + part * 8) = l;
        }
        {   // stage qw3 chunk [128 q][32 d] (pre-split bf16 from ws)
            int q = tid >> 1, part = tid & 1;
            size_t gb = (size_t)q * D_ + k0 + part * 16;
            bf16x8 h0 = *(const bf16x8*)(qw3Hb + gb);
            bf16x8 h1 = *(const bf16x8*)(qw3Hb + gb + 8);
            bf16x8 l0 = *(const bf16x8*)(qw3Lb + gb);
            bf16x8 l1 = *(const bf16x8*)(qw3Lb + gb + 8);
            *(bf16x8*)(QbHi + q * 40 + part * 16)     = h0;
            *(bf16x8*)(QbHi + q * 40 + part * 16 + 8) = h1;
            *(bf16x8*)(QbLo + q * 40 + part * 16)     = l0;
            *(bf16x8*)(QbLo + q * 40 + part * 16 + 8) = l1;
        }
        __syncthreads();
        bf16x8 aH = *(const bf16x8*)(CsHi + (w16 + lm) * 40 + lk);
        bf16x8 aL = *(const bf16x8*)(CsLo + (w16 + lm) * 40 + lk);
        #pragma unroll
        for (int f = 0; f < 8; ++f) {
            bf16x8 bH = *(const bf16x8*)(QbHi + (f * 16 + lm) * 40 + lk);
            bf16x8 bL = *(const bf16x8*)(QbLo + (f * 16 + lm) * 40 + lk);
            acc[f] = __builtin_amdgcn_mfma_f32_16x16x32_bf16(aH, bH, acc[f], 0, 0, 0);
            acc[f] = __builtin_amdgcn_mfma_f32_16x16x32_bf16(aH, bL, acc[f], 0, 0, 0);
            acc[f] = __builtin_amdgcn_mfma_f32_16x16x32_bf16(aL, bH, acc[f], 0, 0, 0);
        }
    }
    __syncthreads();   // all GEMM1 LDS reads done before P overwrites Cs/Qb

    // ---- softmax over q; P -> LDS as bf16 hi/lo; row max -> m_out
    float inv[4];
    #pragma unroll
    for (int r = 0; r < 4; ++r) {
        float sv[8];
        float mx = -3.0e38f;
        #pragma unroll
        for (int f = 0; f < 8; ++f) {
            sv[f] = acc[f][r] + qe[f];
            mx = fmaxf(mx, sv[f]);
        }
        mx = fmaxf(mx, __shfl_xor(mx, 1, 16));
        mx = fmaxf(mx, __shfl_xor(mx, 2, 16));
        mx = fmaxf(mx, __shfl_xor(mx, 4, 16));
        mx = fmaxf(mx, __shfl_xor(mx, 8, 16));
        int lrow = w16 + lg * 4 + r;
        float s = 0.f;
        #pragma unroll
        for (int f = 0; f < 8; ++f) {
            float p = __expf(sv[f] - mx);
            s += p;
            short h, l;
            split_f32(p, h, l);
            PHi[lrow * 136 + f * 16 + lm] = h;
            PLo[lrow * 136 + f * 16 + lm] = l;
        }
        s += __shfl_xor(s, 1, 16);
        s += __shfl_xor(s, 2, 16);
        s += __shfl_xor(s, 4, 16);
        s += __shfl_xor(s, 8, 16);
        inv[r] = 1.0f / s;
        if (lm == 0) m_out[(size_t)b * C_ + c0 + lrow] = mx + cwr[r];
    }

    // ---- GEMM2: c2q[c][d] = sum_q P[c][q] * qry[q][d], K=q in 4 chunks of 32
    f32x4 acc2[8];
    #pragma unroll
    for (int f = 0; f < 8; ++f) acc2[f] = vzero;

    const unsigned short* qTHb = qTHi + (size_t)b * Q_ * D_;
    const unsigned short* qTLb = qTLo + (size_t)b * Q_ * D_;

    for (int q0 = 0; q0 < Q_; q0 += 32) {
        __syncthreads();
        {   // stage qT chunk [128 d][32 q]
            int d = tid >> 1, part = tid & 1;
            size_t gb = (size_t)d * Q_ + q0 + part * 16;
            bf16x8 h0 = *(const bf16x8*)(qTHb + gb);
            bf16x8 h1 = *(const bf16x8*)(qTHb + gb + 8);
            bf16x8 l0 = *(const bf16x8*)(qTLb + gb);
            bf16x8 l1 = *(const bf16x8*)(qTLb + gb + 8);
            *(bf16x8*)(QTh + d * 40 + part * 16)     = h0;
            *(bf16x8*)(QTh + d * 40 + part * 16 + 8) = h1;
            *(bf16x8*)(QTl + d * 40 + part * 16)     = l0;
            *(bf16x8*)(QTl + d * 40 + part * 16 + 8) = l1;
        }
        __syncthreads();
        bf16x8 aH = *(const bf16x8*)(PHi + (w16 + lm) * 136 + q0 + lk);
        bf16x8 aL = *(const bf16x8*)(PLo + (w16 + lm) * 136 + q0 + lk);
        #pragma unroll
        for (int f = 0; f < 8; ++f) {
            bf16x8 bH = *(const bf16x8*)(QTh + (f * 16 + lm) * 40 + lk);
            bf16x8 bL = *(const bf16x8*)(QTl + (f * 16 + lm) * 40 + lk);
            acc2[f] = __builtin_amdgcn_mfma_f32_16x16x32_bf16(aH, bH, acc2[f], 0, 0, 0);
            acc2[f] = __builtin_amdgcn_mfma_f32_16x16x32_bf16(aH, bL, acc2[f], 0, 0, 0);
            acc2[f] = __builtin_amdgcn_mfma_f32_16x16x32_bf16(aL, bH, acc2[f], 0, 0, 0);
        }
    }
    __syncthreads();   // all GEMM2 LDS reads done before Tr overwrites P

    // ---- transpose c2q through LDS, then coalesced stores of out[0:3D)
    #pragma unroll
    for (int r = 0; r < 4; ++r) {
        int lrow = w16 + lg * 4 + r;
        #pragma unroll
        for (int f = 0; f < 8; ++f)
            Tr[lrow * 132 + f * 16 + lm] = acc2[f][r] * inv[r];
    }
    __syncthreads();
    {
        int rsel = tid >> 5;
        int d    = (tid & 31) * 4;
        #pragma unroll
        for (int pass = 0; pass < 8; ++pass) {
            int row = pass * 8 + rsel;
            float4 a  = *(const float4*)(Tr + row * 132 + d);
            float4 cv = *(const float4*)(ctxb + (size_t)row * D_ + d);
            size_t obase = ((size_t)b * C_ + c0 + row) * (4 * D_);
            float4 p;
            p.x = cv.x*a.x; p.y = cv.y*a.y; p.z = cv.z*a.z; p.w = cv.w*a.w;
            *(float4*)(out + obase + d)          = cv;
            *(float4*)(out + obase + D_ + d)     = a;
            *(float4*)(out + obase + 2 * D_ + d) = p;
        }
    }
}

// ---------------- per-batch max / sumexp of m ----------------
__global__ __launch_bounds__(256)
void cqa_bstats(const float* __restrict__ m, float* __restrict__ bstats)
{
    int b = blockIdx.x;
    const float* mb = m + (size_t)b * C_;
    int tid = threadIdx.x;
    float vals[8];
    float mx = -3.0e38f;
    #pragma unroll
    for (int i = 0; i < 8; ++i) {
        vals[i] = mb[tid + i*256];
        mx = fmaxf(mx, vals[i]);
    }
    #pragma unroll
    for (int o = 1; o < 64; o <<= 1) mx = fmaxf(mx, __shfl_xor(mx, o, 64));
    __shared__ float red[4], red2[4];
    int wv = tid >> 6, ln = tid & 63;
    if (ln == 0) red[wv] = mx;
    __syncthreads();
    mx = fmaxf(fmaxf(red[0], red[1]), fmaxf(red[2], red[3]));
    float s = 0.f;
    #pragma unroll
    for (int i = 0; i < 8; ++i) s += __expf(vals[i] - mx);
    #pragma unroll
    for (int o = 1; o < 64; o <<= 1) s += __shfl_xor(s, o, 64);
    if (ln == 0) red2[wv] = s;
    __syncthreads();
    if (tid == 0) {
        bstats[b*2]   = mx;
        bstats[b*2+1] = red2[0] + red2[1] + red2[2] + red2[3];
    }
}

// ---------------- q2c partials (deterministic, no atomics) ----------------
__global__ __launch_bounds__(256)
void cqa_q2c_part(const float* __restrict__ ctx, const float* __restrict__ m,
                  const float* __restrict__ bstats, float* __restrict__ part)
{
    int b = blockIdx.y, ch = blockIdx.x;
    int tid = threadIdx.x;
    int d = tid & 127, half = tid >> 7;
    float bmax = bstats[b*2];
    float inv  = 1.0f / bstats[b*2+1];
    const float* mb = m + (size_t)b*C_ + ch*256;
    const float* cb = ctx + ((size_t)b*C_ + ch*256) * D_;
    float acc = 0.f;
    for (int i = half; i < 256; i += 2) {
        float wgt = __expf(mb[i] - bmax);
        acc += wgt * cb[(size_t)i * D_ + d];
    }
    __shared__ float sh[128];
    if (half) sh[d] = acc;
    __syncthreads();
    if (!half) part[((size_t)b*8 + ch) * D_ + d] = (acc + sh[d]) * inv;
}

__global__ __launch_bounds__(256)
void cqa_q2c_sum(const float* __restrict__ part, float* __restrict__ q2c)
{
    int i = blockIdx.x * 256 + threadIdx.x;
    if (i >= B_ * D_) return;
    int b = i >> 7, d = i & 127;
    float s = 0.f;
    #pragma unroll
    for (int ch = 0; ch < 8; ++ch) s += part[((size_t)b*8 + ch)*D_ + d];
    q2c[i] = s;
}

// ---------------- out[:,:,384:512) = ctx * q2c (broadcast) ----------------
__global__ __launch_bounds__(256)
void cqa_out4(const float* __restrict__ ctx, const float* __restrict__ q2c,
              float* __restrict__ out)
{
    size_t i = (size_t)blockIdx.x * 256 + threadIdx.x;
    const size_t n4 = (size_t)B_*C_*D_/4;
    if (i >= n4) return;
    size_t bc = i >> 5;
    int d4 = (int)(i & 31);
    int b  = (int)(bc >> 11);
    float4 c4 = reinterpret_cast<const float4*>(ctx)[i];
    float4 g4 = reinterpret_cast<const float4*>(q2c)[b*32 + d4];
    float4 o;
    o.x = c4.x*g4.x; o.y = c4.y*g4.y; o.z = c4.z*g4.z; o.w = c4.w*g4.w;
    reinterpret_cast<float4*>(out)[bc*128 + 96 + d4] = o;
}

extern "C" void kernel_launch(void* const* d_in, const int* in_sizes, int n_in,
                              void* d_out, int out_size, void* d_ws, size_t ws_size,
                              hipStream_t stream)
{
    const float* ctx   = (const float*)d_in[0];
    const float* qry   = (const float*)d_in[1];
    const float* w     = (const float*)d_in[2];
    const int*   qmask = (const int*)d_in[3];
    float* out = (float*)d_out;
    float* ws  = (float*)d_ws;

    float* m_ws    = ws;                        // 65536 f32
    float* bstats  = ws + 65536;                // 64 (pad 128)
    float* part    = ws + 65664;                // 32768
    float* q2c     = ws + 98432;                // 4096
    float* qw2e_g  = ws + 102528;               // 4096
    unsigned short* bf = (unsigned short*)(ws + 106624);
    unsigned short* qw3Hi = bf;                 // 524288 each
    unsigned short* qw3Lo = bf + 524288;
    unsigned short* qTHi  = bf + 2*524288;
    unsigned short* qTLo  = bf + 3*524288;

    cqa_prep<<<dim3(8, B_), 256, 0, stream>>>(qry, w, qmask, qw2e_g,
                                              qw3Hi, qw3Lo, qTHi, qTLo);
    cqa_main<<<dim3(C_/CT, B_), 256, 0, stream>>>(ctx, w, qw2e_g,
                                                  qw3Hi, qw3Lo, qTHi, qTLo,
                                                  out, m_ws);
    cqa_bstats<<<B_, 256, 0, stream>>>(m_ws, bstats);
    cqa_q2c_part<<<dim3(8, B_), 256, 0, stream>>>(ctx, m_ws, bstats, part);
    cqa_q2c_sum<<<(B_*D_ + 255)/256, 256, 0, stream>>>(part, q2c);
    cqa_out4<<<(int)(((size_t)B_*C_*D_/4 + 255)/256), 256, 0, stream>>>(ctx, q2c, out);
}

// Round 5
// 105.391 us; speedup vs baseline: 1.0029x; 1.0029x over previous
//
#include <hip/hip_runtime.h>
#include <cstdint>

#define B_ 32
#define C_ 2048
#define Q_ 128
#define D_ 128
#define CT 64
#define NEG_INF_F (-1.0e9f)

typedef __attribute__((ext_vector_type(8))) short bf16x8;
typedef __attribute__((ext_vector_type(4))) float f32x4;

__device__ inline void split_f32(float v, short& h, short& l) {
    unsigned u  = __float_as_uint(v);
    unsigned hb = u & 0xffff0000u;          // truncated bf16 (hi)
    float lo = v - __uint_as_float(hb);     // exact residual
    h = (short)(hb >> 16);
    l = (short)(__float_as_uint(lo) >> 16);
}

// ---------- prep: qw2e (q.w2 + mask), bf16-split of (qry*w3) and qry^T ----------
__global__ __launch_bounds__(256)
void cqa_prep(const float* __restrict__ qry, const float* __restrict__ w,
              const int* __restrict__ qmask, float* __restrict__ qw2e_g,
              unsigned short* __restrict__ qw3Hi, unsigned short* __restrict__ qw3Lo,
              unsigned short* __restrict__ qTHi, unsigned short* __restrict__ qTLo)
{
    const int b = blockIdx.y, ch = blockIdx.x;   // ch: 16-row chunk of q
    const int t = threadIdx.x;
    const float* qb = qry + (size_t)b * Q_ * D_;

    if (t < 32) {
        int rl = t >> 1, part = t & 1;
        int q = ch * 16 + rl;
        const float* p  = qb + q * D_ + part * 64;
        const float* wp = w + D_ + part * 64;
        float s = 0.f;
        #pragma unroll
        for (int j = 0; j < 64; j += 4) {
            float4 a4 = *(const float4*)(p + j);
            float4 w4 = *(const float4*)(wp + j);
            s += a4.x*w4.x + a4.y*w4.y + a4.z*w4.z + a4.w*w4.w;
        }
        s += __shfl_xor(s, 1, 2);
        if (!part) {
            float madd = (1.0f - (float)qmask[b * Q_ + q]) * NEG_INF_F;
            qw2e_g[b * Q_ + q] = s + madd;
        }
    }
    #pragma unroll
    for (int i = 0; i < 8; ++i) {
        int idx = t + i * 256;            // 0..2047 over 16 rows x 128 d
        int ql = idx >> 7, d = idx & 127;
        int q = ch * 16 + ql;
        float v  = qb[q * D_ + d];
        float vw = v * w[2 * D_ + d];
        short h, l;
        split_f32(vw, h, l);
        qw3Hi[((size_t)b * Q_ + q) * D_ + d] = (unsigned short)h;
        qw3Lo[((size_t)b * Q_ + q) * D_ + d] = (unsigned short)l;
        split_f32(v, h, l);
        qTHi[((size_t)b * D_ + d) * Q_ + q] = (unsigned short)h;
        qTLo[((size_t)b * D_ + d) * Q_ + q] = (unsigned short)l;
    }
}

// ---------- main: MFMA S-GEMM + softmax + MFMA PV-GEMM + out[0:3D) ----------
__global__ __launch_bounds__(256, 2)
void cqa_main(const float* __restrict__ ctx, const float* __restrict__ w,
              const float* __restrict__ qw2e_g,
              const unsigned short* __restrict__ qw3Hi, const unsigned short* __restrict__ qw3Lo,
              const unsigned short* __restrict__ qTHi, const unsigned short* __restrict__ qTLo,
              float* __restrict__ out, float* __restrict__ m_out)
{
    __shared__ __align__(16) char smem[56320];
    short* CsHi = (short*)smem;                 // [64][40]  GEMM1
    short* CsLo = (short*)(smem + 5120);
    short* QbHi = (short*)(smem + 10240);       // [128][40] GEMM1
    short* QbLo = (short*)(smem + 20480);       // ..30720
    short* PHi  = (short*)smem;                 // [64][136] GEMM2 (overlays Cs/Qb)
    short* PLo  = (short*)(smem + 17408);       // ..34816
    short* QTh  = (short*)(smem + 34816);       // [128][40] GEMM2
    short* QTl  = (short*)(smem + 45056);       // ..55296
    float* Tr   = (float*)smem;                 // [64][132] epilogue (overlays P)
    float* cw1  = (float*)(smem + 55296);       // 64 f32
    float* qw2e = (float*)(smem + 55552);       // 128 f32

    const int b   = blockIdx.y;
    const int c0  = blockIdx.x * CT;
    const int tid = threadIdx.x;
    const int lane = tid & 63;
    const int wv   = tid >> 6;
    const int w16  = wv * 16;
    const int lm   = lane & 15;
    const int lg   = lane >> 4;    // 0..3
    const int lk   = lg * 8;       // k-slot start within 32-chunk

    const float* ctxb = ctx + ((size_t)b * C_ + c0) * D_;

    // cw1[c] = ctx_row . w1 (4 threads/row)
    {
        int row = tid >> 2, part = tid & 3;
        const float* p  = ctxb + row * D_ + part * 32;
        const float* wp = w + part * 32;
        float s = 0.f;
        #pragma unroll
        for (int j = 0; j < 32; j += 4) {
            float4 c4 = *(const float4*)(p + j);
            float4 w4 = *(const float4*)(wp + j);
            s += c4.x*w4.x + c4.y*w4.y + c4.z*w4.z + c4.w*w4.w;
        }
        s += __shfl_xor(s, 1, 4);
        s += __shfl_xor(s, 2, 4);
        if (!part) cw1[row] = s;
    }
    if (tid < Q_) qw2e[tid] = qw2e_g[b * Q_ + tid];
    __syncthreads();

    float qe[8];
    #pragma unroll
    for (int f = 0; f < 8; ++f) qe[f] = qw2e[f * 16 + lm];
    float cwr[4];
    #pragma unroll
    for (int r = 0; r < 4; ++r) cwr[r] = cw1[w16 + lg * 4 + r];

    const f32x4 vzero = {0.f, 0.f, 0.f, 0.f};
    f32x4 acc[8];
    #pragma unroll
    for (int f = 0; f < 8; ++f) acc[f] = vzero;

    const unsigned short* qw3Hb = qw3Hi + (size_t)b * Q_ * D_;
    const unsigned short* qw3Lb = qw3Lo + (size_t)b * Q_ * D_;

    // ---- GEMM1: S[c][q] (wave: 16 rows x 128 cols), K=d in 4 chunks of 32
    for (int k0 = 0; k0 < D_; k0 += 32) {
        __syncthreads();
        {   // stage ctx chunk 64x32 f32 -> bf16 hi/lo
            int row = tid >> 2, part = tid & 3;
            const float* p = ctxb + row * D_ + k0 + part * 8;
            float4 v0 = *(const float4*)p;
            float4 v1 = *(const float4*)(p + 4);
            float vv[8] = {v0.x,v0.y,v0.z,v0.w,v1.x,v1.y,v1.z,v1.w};
            bf16x8 h, l;
            #pragma unroll
            for (int i = 0; i < 8; ++i) { short hh, ll; split_f32(vv[i], hh, ll); h[i]=hh; l[i]=ll; }
            *(bf16x8*)(CsHi + row * 40 + part * 8) = h;
            *(bf16x8*)(CsLo + row * 40 + part * 8) = l;
        }
        {   // stage qw3 chunk [128 q][32 d] (pre-split bf16 from ws)
            int q = tid >> 1, part = tid & 1;
            size_t gb = (size_t)q * D_ + k0 + part * 16;
            bf16x8 h0 = *(const bf16x8*)(qw3Hb + gb);
            bf16x8 h1 = *(const bf16x8*)(qw3Hb + gb + 8);
            bf16x8 l0 = *(const bf16x8*)(qw3Lb + gb);
            bf16x8 l1 = *(const bf16x8*)(qw3Lb + gb + 8);
            *(bf16x8*)(QbHi + q * 40 + part * 16)     = h0;
            *(bf16x8*)(QbHi + q * 40 + part * 16 + 8) = h1;
            *(bf16x8*)(QbLo + q * 40 + part * 16)     = l0;
            *(bf16x8*)(QbLo + q * 40 + part * 16 + 8) = l1;
        }
        __syncthreads();
        bf16x8 aH = *(const bf16x8*)(CsHi + (w16 + lm) * 40 + lk);
        bf16x8 aL = *(const bf16x8*)(CsLo + (w16 + lm) * 40 + lk);
        #pragma unroll
        for (int f = 0; f < 8; ++f) {
            bf16x8 bH = *(const bf16x8*)(QbHi + (f * 16 + lm) * 40 + lk);
            bf16x8 bL = *(const bf16x8*)(QbLo + (f * 16 + lm) * 40 + lk);
            acc[f] = __builtin_amdgcn_mfma_f32_16x16x32_bf16(aH, bH, acc[f], 0, 0, 0);
            acc[f] = __builtin_amdgcn_mfma_f32_16x16x32_bf16(aH, bL, acc[f], 0, 0, 0);
            acc[f] = __builtin_amdgcn_mfma_f32_16x16x32_bf16(aL, bH, acc[f], 0, 0, 0);
        }
    }
    __syncthreads();   // all GEMM1 LDS reads done before P overwrites Cs/Qb

    // ---- softmax over q; P -> LDS as bf16 hi/lo; row max -> m_out
    float inv[4];
    #pragma unroll
    for (int r = 0; r < 4; ++r) {
        float sv[8];
        float mx = -3.0e38f;
        #pragma unroll
        for (int f = 0; f < 8; ++f) {
            sv[f] = acc[f][r] + qe[f];
            mx = fmaxf(mx, sv[f]);
        }
        mx = fmaxf(mx, __shfl_xor(mx, 1, 16));
        mx = fmaxf(mx, __shfl_xor(mx, 2, 16));
        mx = fmaxf(mx, __shfl_xor(mx, 4, 16));
        mx = fmaxf(mx, __shfl_xor(mx, 8, 16));
        int lrow = w16 + lg * 4 + r;
        float s = 0.f;
        #pragma unroll
        for (int f = 0; f < 8; ++f) {
            float p = __expf(sv[f] - mx);
            s += p;
            short h, l;
            split_f32(p, h, l);
            PHi[lrow * 136 + f * 16 + lm] = h;
            PLo[lrow * 136 + f * 16 + lm] = l;
        }
        s += __shfl_xor(s, 1, 16);
        s += __shfl_xor(s, 2, 16);
        s += __shfl_xor(s, 4, 16);
        s += __shfl_xor(s, 8, 16);
        inv[r] = 1.0f / s;
        if (lm == 0) m_out[(size_t)b * C_ + c0 + lrow] = mx + cwr[r];
    }

    // ---- GEMM2: c2q[c][d] = sum_q P[c][q] * qry[q][d], K=q in 4 chunks of 32
    f32x4 acc2[8];
    #pragma unroll
    for (int f = 0; f < 8; ++f) acc2[f] = vzero;

    const unsigned short* qTHb = qTHi + (size_t)b * Q_ * D_;
    const unsigned short* qTLb = qTLo + (size_t)b * Q_ * D_;

    for (int q0 = 0; q0 < Q_; q0 += 32) {
        __syncthreads();
        {   // stage qT chunk [128 d][32 q]
            int d = tid >> 1, part = tid & 1;
            size_t gb = (size_t)d * Q_ + q0 + part * 16;
            bf16x8 h0 = *(const bf16x8*)(qTHb + gb);
            bf16x8 h1 = *(const bf16x8*)(qTHb + gb + 8);
            bf16x8 l0 = *(const bf16x8*)(qTLb + gb);
            bf16x8 l1 = *(const bf16x8*)(qTLb + gb + 8);
            *(bf16x8*)(QTh + d * 40 + part * 16)     = h0;
            *(bf16x8*)(QTh + d * 40 + part * 16 + 8) = h1;
            *(bf16x8*)(QTl + d * 40 + part * 16)     = l0;
            *(bf16x8*)(QTl + d * 40 + part * 16 + 8) = l1;
        }
        __syncthreads();
        bf16x8 aH = *(const bf16x8*)(PHi + (w16 + lm) * 136 + q0 + lk);
        bf16x8 aL = *(const bf16x8*)(PLo + (w16 + lm) * 136 + q0 + lk);
        #pragma unroll
        for (int f = 0; f < 8; ++f) {
            bf16x8 bH = *(const bf16x8*)(QTh + (f * 16 + lm) * 40 + lk);
            bf16x8 bL = *(const bf16x8*)(QTl + (f * 16 + lm) * 40 + lk);
            acc2[f] = __builtin_amdgcn_mfma_f32_16x16x32_bf16(aH, bH, acc2[f], 0, 0, 0);
            acc2[f] = __builtin_amdgcn_mfma_f32_16x16x32_bf16(aH, bL, acc2[f], 0, 0, 0);
            acc2[f] = __builtin_amdgcn_mfma_f32_16x16x32_bf16(aL, bH, acc2[f], 0, 0, 0);
        }
    }
    __syncthreads();   // all GEMM2 LDS reads done before Tr overwrites P

    // ---- transpose c2q through LDS, then coalesced stores of out[0:3D)
    #pragma unroll
    for (int r = 0; r < 4; ++r) {
        int lrow = w16 + lg * 4 + r;
        #pragma unroll
        for (int f = 0; f < 8; ++f)
            Tr[lrow * 132 + f * 16 + lm] = acc2[f][r] * inv[r];
    }
    __syncthreads();
    {
        int rsel = tid >> 5;
        int d    = (tid & 31) * 4;
        #pragma unroll
        for (int pass = 0; pass < 8; ++pass) {
            int row = pass * 8 + rsel;
            float4 a  = *(const float4*)(Tr + row * 132 + d);
            float4 cv = *(const float4*)(ctxb + (size_t)row * D_ + d);
            size_t obase = ((size_t)b * C_ + c0 + row) * (4 * D_);
            float4 p;
            p.x = cv.x*a.x; p.y = cv.y*a.y; p.z = cv.z*a.z; p.w = cv.w*a.w;
            *(float4*)(out + obase + d)          = cv;
            *(float4*)(out + obase + D_ + d)     = a;
            *(float4*)(out + obase + 2 * D_ + d) = p;
        }
    }
}

// ---------------- per-batch max / sumexp of m ----------------
__global__ __launch_bounds__(256)
void cqa_bstats(const float* __restrict__ m, float* __restrict__ bstats)
{
    int b = blockIdx.x;
    const float* mb = m + (size_t)b * C_;
    int tid = threadIdx.x;
    float vals[8];
    float mx = -3.0e38f;
    #pragma unroll
    for (int i = 0; i < 8; ++i) {
        vals[i] = mb[tid + i*256];
        mx = fmaxf(mx, vals[i]);
    }
    #pragma unroll
    for (int o = 1; o < 64; o <<= 1) mx = fmaxf(mx, __shfl_xor(mx, o, 64));
    __shared__ float red[4], red2[4];
    int wv = tid >> 6, ln = tid & 63;
    if (ln == 0) red[wv] = mx;
    __syncthreads();
    mx = fmaxf(fmaxf(red[0], red[1]), fmaxf(red[2], red[3]));
    float s = 0.f;
    #pragma unroll
    for (int i = 0; i < 8; ++i) s += __expf(vals[i] - mx);
    #pragma unroll
    for (int o = 1; o < 64; o <<= 1) s += __shfl_xor(s, o, 64);
    if (ln == 0) red2[wv] = s;
    __syncthreads();
    if (tid == 0) {
        bstats[b*2]   = mx;
        bstats[b*2+1] = red2[0] + red2[1] + red2[2] + red2[3];
    }
}

// ---------------- q2c partials (deterministic, no atomics) ----------------
__global__ __launch_bounds__(256)
void cqa_q2c_part(const float* __restrict__ ctx, const float* __restrict__ m,
                  const float* __restrict__ bstats, float* __restrict__ part)
{
    int b = blockIdx.y, ch = blockIdx.x;
    int tid = threadIdx.x;
    int d = tid & 127, half = tid >> 7;
    float bmax = bstats[b*2];
    float inv  = 1.0f / bstats[b*2+1];
    const float* mb = m + (size_t)b*C_ + ch*256;
    const float* cb = ctx + ((size_t)b*C_ + ch*256) * D_;
    float acc = 0.f;
    for (int i = half; i < 256; i += 2) {
        float wgt = __expf(mb[i] - bmax);
        acc += wgt * cb[(size_t)i * D_ + d];
    }
    __shared__ float sh[128];
    if (half) sh[d] = acc;
    __syncthreads();
    if (!half) part[((size_t)b*8 + ch) * D_ + d] = (acc + sh[d]) * inv;
}

__global__ __launch_bounds__(256)
void cqa_q2c_sum(const float* __restrict__ part, float* __restrict__ q2c)
{
    int i = blockIdx.x * 256 + threadIdx.x;
    if (i >= B_ * D_) return;
    int b = i >> 7, d = i & 127;
    float s = 0.f;
    #pragma unroll
    for (int ch = 0; ch < 8; ++ch) s += part[((size_t)b*8 + ch)*D_ + d];
    q2c[i] = s;
}

// ---------------- out[:,:,384:512) = ctx * q2c (broadcast) ----------------
__global__ __launch_bounds__(256)
void cqa_out4(const float* __restrict__ ctx, const float* __restrict__ q2c,
              float* __restrict__ out)
{
    size_t i = (size_t)blockIdx.x * 256 + threadIdx.x;
    const size_t n4 = (size_t)B_*C_*D_/4;
    if (i >= n4) return;
    size_t bc = i >> 5;
    int d4 = (int)(i & 31);
    int b  = (int)(bc >> 11);
    float4 c4 = reinterpret_cast<const float4*>(ctx)[i];
    float4 g4 = reinterpret_cast<const float4*>(q2c)[b*32 + d4];
    float4 o;
    o.x = c4.x*g4.x; o.y = c4.y*g4.y; o.z = c4.z*g4.z; o.w = c4.w*g4.w;
    reinterpret_cast<float4*>(out)[bc*128 + 96 + d4] = o;
}

extern "C" void kernel_launch(void* const* d_in, const int* in_sizes, int n_in,
                              void* d_out, int out_size, void* d_ws, size_t ws_size,
                              hipStream_t stream)
{
    const float* ctx   = (const float*)d_in[0];
    const float* qry   = (const float*)d_in[1];
    const float* w     = (const float*)d_in[2];
    const int*   qmask = (const int*)d_in[3];
    float* out = (float*)d_out;
    float* ws  = (float*)d_ws;

    float* m_ws    = ws;                        // 65536 f32
    float* bstats  = ws + 65536;                // 64 (pad 128)
    float* part    = ws + 65664;                // 32768
    float* q2c     = ws + 98432;                // 4096
    float* qw2e_g  = ws + 102528;               // 4096
    unsigned short* bf = (unsigned short*)(ws + 106624);
    unsigned short* qw3Hi = bf;                 // 524288 each
    unsigned short* qw3Lo = bf + 524288;
    unsigned short* qTHi  = bf + 2*524288;
    unsigned short* qTLo  = bf + 3*524288;

    cqa_prep<<<dim3(8, B_), 256, 0, stream>>>(qry, w, qmask, qw2e_g,
                                              qw3Hi, qw3Lo, qTHi, qTLo);
    cqa_main<<<dim3(C_/CT, B_), 256, 0, stream>>>(ctx, w, qw2e_g,
                                                  qw3Hi, qw3Lo, qTHi, qTLo,
                                                  out, m_ws);
    cqa_bstats<<<B_, 256, 0, stream>>>(m_ws, bstats);
    cqa_q2c_part<<<dim3(8, B_), 256, 0, stream>>>(ctx, m_ws, bstats, part);
    cqa_q2c_sum<<<(B_*D_ + 255)/256, 256, 0, stream>>>(part, q2c);
    cqa_out4<<<(int)(((size_t)B_*C_*D_/4 + 255)/256), 256, 0, stream>>>(ctx, q2c, out);
}